// Round 12
// baseline (1799.384 us; speedup 1.0000x reference)
//
#include <hip/hip_runtime.h>
#include <cstddef>

#define Bg 128
#define Nn 100
#define Eg 800
#define TNODE 12800
#define TEDGE 102400
#define HD 256
#define NEMB 128
#define REMB 256

typedef short bf8 __attribute__((ext_vector_type(8)));
typedef short bf4 __attribute__((ext_vector_type(4)));
typedef float f4  __attribute__((ext_vector_type(4)));

__device__ __forceinline__ float relu_(float x){ return x > 0.f ? x : 0.f; }
__device__ __forceinline__ float sigm_(float x){ return 1.f/(1.f + __expf(-x)); }
__device__ __forceinline__ float4 ld4(const float* p){ return *(const float4*)p; }
__device__ __forceinline__ void st4(float* p, float4 v){ *(float4*)p = v; }
__device__ __forceinline__ float4 add4(float4 a, float4 b){
    return float4{a.x+b.x, a.y+b.y, a.z+b.z, a.w+b.w};
}
__device__ __forceinline__ float4 relu4(float4 a){
    return float4{relu_(a.x), relu_(a.y), relu_(a.z), relu_(a.w)};
}
__device__ __forceinline__ short f2bf(float f){
    unsigned u = __float_as_uint(f);
    u += 0x7fff + ((u >> 16) & 1);
    return (short)(u >> 16);
}
__device__ __forceinline__ float bf2f(short s){
    return __uint_as_float(((unsigned)(unsigned short)s) << 16);
}
__device__ __forceinline__ void split4(float4 v, bf4& h, bf4& l){
    h.x = f2bf(v.x); l.x = f2bf(v.x - bf2f(h.x));
    h.y = f2bf(v.y); l.y = f2bf(v.y - bf2f(h.y));
    h.z = f2bf(v.z); l.z = f2bf(v.z - bf2f(h.z));
    h.w = f2bf(v.w); l.w = f2bf(v.w - bf2f(h.w));
}
__device__ __forceinline__ f4 mfma_(bf8 a, bf8 b, f4 c){
    return __builtin_amdgcn_mfma_f32_16x16x32_bf16(a, b, c, 0, 0, 0);
}

enum { A_PLAIN=0, A_ADD=1, A_RELUB=2, A_CLAMP=3, A_CAT3=4, A_CAT2R=5 };
enum { E_STORE=0, E_RELU=1, E_BIAS=2, E_BIASRELU=3 };

// ---------- MFMA split-bf16 GEMM: C[M,N] = epi(A[M,K] @ W[N,K]^T), ~f32 accuracy ----------
template<int AM, int EM>
__global__ __launch_bounds__(256, 2)
void mgemm(const float* __restrict__ A0, const float* __restrict__ A1,
           const float* __restrict__ A2, const float* __restrict__ W,
           const float* __restrict__ bias, float* __restrict__ C,
           int M, int N, int K, int lda, int wld)
{
    __shared__ short Ah[128][40], Al[128][40], Bh[128][40], Bl[128][40];
    const int t  = threadIdx.x;
    const int kc = t & 7, lr = t >> 3;
    const int lane = t & 63, wv = t >> 6;
    const int wm = wv >> 1, wn = wv & 1;
    const int frow = lane & 15, fk = (lane >> 4) * 8;
    const int row0 = blockIdx.y * 128, col0 = blockIdx.x * 128;

    f4 acc[4][4] = {};

    for (int k0 = 0; k0 < K; k0 += 32) {
        const int gk = k0 + kc * 4;
        const int kk = kc * 4;
        #pragma unroll
        for (int ri = 0; ri < 4; ri++) {
            int row = lr + 32 * ri;
            int grow = row0 + row;
            float4 v;
            if (AM == A_PLAIN) {
                v = ld4(A0 + (size_t)grow * lda + gk);
            } else if (AM == A_ADD) {
                v = add4(ld4(A0 + (size_t)grow * lda + gk),
                         ld4(A1 + (size_t)grow * lda + gk));
            } else if (AM == A_RELUB) {
                v = relu4(add4(ld4(A0 + (size_t)grow * lda + gk), ld4(A1 + gk)));
            } else if (AM == A_CLAMP) {
                int cr = grow < M ? grow : M - 1;
                v = ld4(A0 + (size_t)cr * lda + gk);
            } else if (AM == A_CAT3) {
                if (gk < HD)        v = ld4(A0 + (size_t)grow * HD + gk);
                else if (gk < 2*HD) v = ld4(A1 + (size_t)grow * HD + gk - HD);
                else                v = ld4(A2 + (size_t)grow * HD + gk - 2*HD);
            } else { // A_CAT2R
                v = (gk < HD) ? relu4(ld4(A0 + (size_t)grow * HD + gk))
                              : relu4(ld4(A1 + (size_t)grow * HD + gk - HD));
            }
            bf4 h, l; split4(v, h, l);
            *(bf4*)&Ah[row][kk] = h;
            *(bf4*)&Al[row][kk] = l;
        }
        #pragma unroll
        for (int ri = 0; ri < 4; ri++) {
            int wr = lr + 32 * ri;
            float4 v = ld4(W + (size_t)(col0 + wr) * wld + gk);
            bf4 h, l; split4(v, h, l);
            *(bf4*)&Bh[wr][kk] = h;
            *(bf4*)&Bl[wr][kk] = l;
        }
        __syncthreads();
        bf8 ah[4], al[4], bh[4], bl[4];
        #pragma unroll
        for (int mi = 0; mi < 4; mi++) {
            ah[mi] = *(const bf8*)&Ah[wm*64 + mi*16 + frow][fk];
            al[mi] = *(const bf8*)&Al[wm*64 + mi*16 + frow][fk];
        }
        #pragma unroll
        for (int ni = 0; ni < 4; ni++) {
            bh[ni] = *(const bf8*)&Bh[wn*64 + ni*16 + frow][fk];
            bl[ni] = *(const bf8*)&Bl[wn*64 + ni*16 + frow][fk];
        }
        #pragma unroll
        for (int mi = 0; mi < 4; mi++)
            #pragma unroll
            for (int ni = 0; ni < 4; ni++) {
                acc[mi][ni] = mfma_(ah[mi], bh[ni], acc[mi][ni]);
                acc[mi][ni] = mfma_(ah[mi], bl[ni], acc[mi][ni]);
                acc[mi][ni] = mfma_(al[mi], bh[ni], acc[mi][ni]);
            }
        __syncthreads();
    }
    #pragma unroll
    for (int mi = 0; mi < 4; mi++) {
        #pragma unroll
        for (int ni = 0; ni < 4; ni++) {
            int ccol = col0 + wn*64 + ni*16 + frow;
            int rbase = row0 + wm*64 + mi*16 + (lane >> 4) * 4;
            #pragma unroll
            for (int reg = 0; reg < 4; reg++) {
                float v = acc[mi][ni][reg];
                if (EM == E_BIAS || EM == E_BIASRELU) v += bias[ccol];
                if (EM == E_RELU || EM == E_BIASRELU) v = relu_(v);
                C[(size_t)(rbase + reg) * N + ccol] = v;
            }
        }
    }
}

// ---------- MFMA attention over reconstructed edge features ----------
template<int MODE>
__global__ __launch_bounds__(256, 2)
void mattn(const float* __restrict__ S, const float* __restrict__ Rt,
           const float* __restrict__ D, const float* __restrict__ T0,
           const int* __restrict__ esrc, const int* __restrict__ erel,
           const int* __restrict__ edst,
           const float* __restrict__ W1, const float* __restrict__ W2,
           const float* __restrict__ term, float* __restrict__ sbuf)
{
    __shared__ short Ah[64][40], Al[64][40], Bh[256][40], Bl[256][40];
    __shared__ float partl[4][64];
    __shared__ int isrc[64], irel[64], idst[64];
    const int t = threadIdx.x;
    const int kc = t & 7, lr = t >> 3;
    const int lane = t & 63, wv = t >> 6;
    const int frow = lane & 15, fk = (lane >> 4) * 8;
    const int r0 = blockIdx.x * 64;

    if (t < 64) {
        int e = r0 + t;
        isrc[t] = esrc[e]; irel[t] = erel[e]; idst[t] = edst[e];
    }
    __syncthreads();

    f4 acc[4][4] = {};

    for (int k0 = 0; k0 < HD; k0 += 32) {
        const int gk = k0 + kc * 4;
        const int kk = kc * 4;
        #pragma unroll
        for (int ri = 0; ri < 2; ri++) {
            int row = lr + 32 * ri;
            int s = isrc[row], rl = irel[row], dd = idst[row];
            float4 v = relu4(add4(add4(ld4(S + (size_t)s * HD + gk),
                                       ld4(Rt + (size_t)rl * HD + gk)),
                                  ld4(D + (size_t)dd * HD + gk)));
            if (MODE) v = relu4(add4(v, ld4(T0 + (size_t)s * HD + gk)));
            bf4 h, l; split4(v, h, l);
            *(bf4*)&Ah[row][kk] = h;
            *(bf4*)&Al[row][kk] = l;
        }
        #pragma unroll
        for (int ri = 0; ri < 8; ri++) {
            int wr = lr + 32 * ri;
            float4 v = ld4(W1 + (size_t)wr * 512 + gk);   // left half of [256,512]
            bf4 h, l; split4(v, h, l);
            *(bf4*)&Bh[wr][kk] = h;
            *(bf4*)&Bl[wr][kk] = l;
        }
        __syncthreads();
        bf8 ah[4], al[4], bh[4], bl[4];
        #pragma unroll
        for (int mi = 0; mi < 4; mi++) {
            ah[mi] = *(const bf8*)&Ah[mi*16 + frow][fk];
            al[mi] = *(const bf8*)&Al[mi*16 + frow][fk];
        }
        #pragma unroll
        for (int ni = 0; ni < 4; ni++) {
            bh[ni] = *(const bf8*)&Bh[wv*64 + ni*16 + frow][fk];
            bl[ni] = *(const bf8*)&Bl[wv*64 + ni*16 + frow][fk];
        }
        #pragma unroll
        for (int mi = 0; mi < 4; mi++)
            #pragma unroll
            for (int ni = 0; ni < 4; ni++) {
                acc[mi][ni] = mfma_(ah[mi], bh[ni], acc[mi][ni]);
                acc[mi][ni] = mfma_(ah[mi], bl[ni], acc[mi][ni]);
                acc[mi][ni] = mfma_(al[mi], bh[ni], acc[mi][ni]);
            }
        __syncthreads();
    }
    #pragma unroll
    for (int mi = 0; mi < 4; mi++) {
        #pragma unroll
        for (int reg = 0; reg < 4; reg++) {
            int rl = mi*16 + (lane >> 4) * 4 + reg;
            int g = (r0 + rl) / Eg;
            float p = 0.f;
            #pragma unroll
            for (int ni = 0; ni < 4; ni++) {
                int n = wv*64 + ni*16 + frow;
                p += tanhf(acc[mi][ni][reg] + term[g*HD + n]) * W2[n];
            }
            p += __shfl_xor(p, 1); p += __shfl_xor(p, 2);
            p += __shfl_xor(p, 4); p += __shfl_xor(p, 8);
            if (frow == 0) partl[wv][rl] = p;
        }
    }
    __syncthreads();
    if (t < 64) {
        float p = partl[0][t] + partl[1][t] + partl[2][t] + partl[3][t];
        sbuf[r0 + t] = sigm_(p);
    }
}

// ------- CSR-gather aggregation: agg[n] = sum_{e: dst[e]==n} me(e) * s[e] -------
template<int MODE>
__global__ __launch_bounds__(256)
void agg_gather(const float* __restrict__ S, const float* __restrict__ Rt,
                const float* __restrict__ D, const float* __restrict__ T0,
                const int* __restrict__ esrc, const int* __restrict__ erel,
                const int* __restrict__ rowptr, const int* __restrict__ eidx,
                const float* __restrict__ s, float* __restrict__ agg)
{
    int node = blockIdx.x * 4 + (threadIdx.x >> 6);
    int c = (threadIdx.x & 63) * 4;
    float4 dn = ld4(D + (size_t)node * HD + c);   // dst row constant per node
    float4 acc{0.f, 0.f, 0.f, 0.f};
    int beg = rowptr[node], end = rowptr[node + 1];
    for (int i = beg; i < end; i++) {
        int e = eidx[i];
        int sr = esrc[e], rl = erel[e];
        float4 v = relu4(add4(add4(ld4(S + (size_t)sr * HD + c),
                                   ld4(Rt + (size_t)rl * HD + c)), dn));
        if (MODE) v = relu4(add4(v, ld4(T0 + (size_t)sr * HD + c)));
        float sc = s[e];
        acc.x += v.x * sc; acc.y += v.y * sc;
        acc.z += v.z * sc; acc.w += v.w * sc;
    }
    st4(agg + (size_t)node * HD + c, acc);
}

// ------------- CSR build -------------
__global__ void zeroi_kernel(int* __restrict__ p)
{
    p[blockIdx.x * 256 + threadIdx.x] = 0;
}
__global__ void csr_count(const int* __restrict__ dst, int* __restrict__ cnt)
{
    int e = blockIdx.x * 256 + threadIdx.x;
    atomicAdd(&cnt[dst[e]], 1);
}
__global__ void csr_scan(const int* __restrict__ cnt, int* __restrict__ rowptr)
{
    __shared__ int ws[4];
    __shared__ int carry;
    int tid = threadIdx.x;
    if (tid == 0) carry = 0;
    __syncthreads();
    for (int i = 0; i < TNODE; i += 256) {
        int v = cnt[i + tid];
        int x = v;
        #pragma unroll
        for (int off = 1; off < 64; off <<= 1) {
            int y = __shfl_up(x, off);
            if ((tid & 63) >= off) x += y;
        }
        if ((tid & 63) == 63) ws[tid >> 6] = x;
        __syncthreads();
        int add = carry;
        int w = tid >> 6;
        for (int j = 0; j < w; j++) add += ws[j];
        rowptr[i + tid] = add + x - v;      // exclusive
        __syncthreads();
        if (tid == 255) carry = add + x;
        __syncthreads();
    }
    if (tid == 0) rowptr[TNODE] = carry;
}
__global__ void csr_fill(const int* __restrict__ dst, const int* __restrict__ rowptr,
                         int* __restrict__ fillc, int* __restrict__ eidx)
{
    int e = blockIdx.x * 256 + threadIdx.x;
    int d = dst[e];
    int slot = rowptr[d] + atomicAdd(&fillc[d], 1);
    eidx[slot] = e;
}

// ------------- per-graph attention bias terms -------------
__global__ __launch_bounds__(256)
void term_kernel(const float* __restrict__ mn, const float* __restrict__ tgt_rel,
                 const float* __restrict__ Wa1, const float* __restrict__ Wd1,
                 const int* __restrict__ srcn, const int* __restrict__ tgtn,
                 float* __restrict__ term)
{
    __shared__ float Gs[HD];
    int b = blockIdx.x % Bg;
    int which = blockIdx.x / Bg;
    int c = threadIdx.x;
    float g;
    if (which == 0)
        g = mn[(size_t)srcn[b]*HD + c] + tgt_rel[b*HD + c] - mn[(size_t)tgtn[b]*HD + c];
    else
        g = tgt_rel[b*HD + c];
    Gs[c] = g;
    __syncthreads();
    const float* W = (which == 0) ? Wa1 : (Wd1 + (size_t)(which-1)*HD*512);
    float p = 0.f;
    for (int k = 0; k < HD; k += 4) {
        float4 w = ld4(W + (size_t)c*512 + 256 + k);
        p = fmaf(Gs[k], w.x, p); p = fmaf(Gs[k+1], w.y, p);
        p = fmaf(Gs[k+2], w.z, p); p = fmaf(Gs[k+3], w.w, p);
    }
    term[(size_t)which*Bg*HD + b*HD + c] = p;
}

__global__ void tgtrel_kernel(const float* __restrict__ rel_emb, const int* __restrict__ batch_rel,
                              float* __restrict__ tgt_rel)
{
    int b = blockIdx.x, c = threadIdx.x;
    tgt_rel[b*HD + c] = rel_emb[(size_t)batch_rel[b]*REMB + c];
}

__global__ void h0_kernel(const float* __restrict__ agg2, float* __restrict__ h0)
{
    int b = blockIdx.x, c = threadIdx.x;
    float m = -1e30f;
    for (int n = 0; n < Nn; n++)
        m = fmaxf(m, agg2[((size_t)b*Nn + n)*HD + c]);
    h0[b*HD + c] = m;
}

// ------------- convert w_hh to bf16: whbf[d][row][k] -------------
__global__ void whbf_kernel(const float* __restrict__ whf, const float* __restrict__ whb,
                            short* __restrict__ whbf)
{
    int idx = blockIdx.x * 256 + threadIdx.x;   // 2*768*256
    int d = idx / (768*256), rem = idx % (768*256);
    whbf[idx] = f2bf((d ? whb : whf)[rem]);
}

// ------------- combined gi bias: bc[d] = b_ih + (r,z part of b_hh) -------------
__global__ void biascomb_kernel(const float* __restrict__ bihf, const float* __restrict__ bhhf,
                                const float* __restrict__ bihb, const float* __restrict__ bhhb,
                                float* __restrict__ bc)
{
    int i = blockIdx.x * 256 + threadIdx.x;   // 1536
    int d = i / 768, r = i % 768;
    const float* bi = d ? bihb : bihf;
    const float* bhh = d ? bhhb : bhhf;
    bc[i] = bi[r] + (r < 512 ? bhh[r] : 0.f);
}

// ------------- GRU: 16 blocks x 256 thr (4 waves, 1 wave/SIMD) -------------
// Weight panel FULLY VGPR-RESIDENT: each wave owns 12 n-tiles (384 VGPRs), loaded once.
// launch_bounds(256,1) -> up to 512 VGPRs available, so the allocator can keep them.
// b_hh r/z folded into gi bias upstream; b_hh_n in 16 regs. A from pre-split LDS.
__global__ __launch_bounds__(256, 1)
void gru_seq(const float* __restrict__ gi_f, const float* __restrict__ gi_b,
             const short* __restrict__ whbf,
             const float* __restrict__ bhf, const float* __restrict__ bhb,
             const float* __restrict__ h0,
             float* __restrict__ outf, float* __restrict__ outb)
{
    __shared__ float hsf[16][260];      // h state f32
    __shared__ short hsh[16][264];      // h bf16 hi
    __shared__ short hsl[16][264];      // h bf16 lo
    __shared__ float gates[768][17];    // [gate*256+h][seq]
    const int blk = blockIdx.x;         // dir*8 + grp
    const int d = blk >> 3, grp = blk & 7;
    const int tid = threadIdx.x;
    const int lane = tid & 63, wv = tid >> 6;   // 4 waves
    const int f16 = lane & 15;
    const int kb  = (lane >> 4) * 8;

    const short* wp0 = whbf + (size_t)d * 768 * 256;
    const float* gi  = d ? gi_b : gi_f;
    const float* bh  = d ? bhb : bhf;
    float* outp      = d ? outb : outf;

    // ---- weight panel -> registers: wave wv owns rows [(wv*12+j)*16, +16), j=0..11 ----
    bf8 wreg[12][8];
    #pragma unroll
    for (int j = 0; j < 12; j++) {
        int wr = (wv*12 + j) * 16 + f16;
        const short* wp = wp0 + (size_t)wr * 256 + kb;
        #pragma unroll
        for (int ks = 0; ks < 8; ks++)
            wreg[j][ks] = *(const bf8*)(wp + ks*32);
    }

    const int eseq = tid >> 4;            // 16 threads per seq
    const int eh0  = (tid & 15) * 16;     // 16 consecutive h per thread
    float bhn[16];
    #pragma unroll
    for (int hh = 0; hh < 16; hh++) bhn[hh] = bh[512 + eh0 + hh];

    {   // init h: f32 + hi/lo split
        #pragma unroll
        for (int hh = 0; hh < 16; hh++) {
            int h = eh0 + hh;
            float v = h0[(size_t)(grp*16 + eseq) * HD + h];
            hsf[eseq][h] = v;
            short hi = f2bf(v);
            hsh[eseq][h] = hi;
            hsl[eseq][h] = f2bf(v - bf2f(hi));
        }
    }
    __syncthreads();

    for (int t = 0; t < Nn; t++) {
        int trow = d ? (Nn - 1 - t) : t;
        // --- MFMA: 3 groups of 4 tiles (acc pressure 16 regs); A from LDS per group ---
        #pragma unroll
        for (int g = 0; g < 3; g++) {
            f4 acc0 = {}, acc1 = {}, acc2 = {}, acc3 = {};
            #pragma unroll
            for (int ks = 0; ks < 8; ks++) {
                bf8 ahi = *(const bf8*)&hsh[f16][ks*32 + kb];
                bf8 alo = *(const bf8*)&hsl[f16][ks*32 + kb];
                acc0 = mfma_(ahi, wreg[g*4+0][ks], acc0);
                acc1 = mfma_(ahi, wreg[g*4+1][ks], acc1);
                acc2 = mfma_(ahi, wreg[g*4+2][ks], acc2);
                acc3 = mfma_(ahi, wreg[g*4+3][ks], acc3);
                acc0 = mfma_(alo, wreg[g*4+0][ks], acc0);
                acc1 = mfma_(alo, wreg[g*4+1][ks], acc1);
                acc2 = mfma_(alo, wreg[g*4+2][ks], acc2);
                acc3 = mfma_(alo, wreg[g*4+3][ks], acc3);
            }
            int rb = (wv*12 + g*4) * 16 + f16;
            int cb = (lane >> 4) * 4;
            #pragma unroll
            for (int reg = 0; reg < 4; reg++) {
                gates[rb +  0][cb + reg] = acc0[reg];
                gates[rb + 16][cb + reg] = acc1[reg];
                gates[rb + 32][cb + reg] = acc2[reg];
                gates[rb + 48][cb + reg] = acc3[reg];
            }
        }
        __syncthreads();
        // --- epilogue: thread owns (eseq, eh0..eh0+15), chunks of 4 ---
        {
            size_t girow = ((size_t)(grp*16 + eseq) * Nn + trow) * 768;
            size_t orow  = ((size_t)(grp*16 + eseq) * Nn + trow) * HD;
            #pragma unroll
            for (int c2 = 0; c2 < 4; c2++) {
                int hb = eh0 + c2*4;
                float4 g_r = ld4(gi + girow + hb);
                float4 g_z = ld4(gi + girow + 256 + hb);
                float4 g_n = ld4(gi + girow + 512 + hb);
                float4 onew;
                #pragma unroll
                for (int e = 0; e < 4; e++) {
                    int h = hb + e;
                    float R  = gates[h][eseq];
                    float Z  = gates[256 + h][eseq];
                    float NN = gates[512 + h][eseq];
                    float hprev = hsf[eseq][h];
                    float gre = ((const float*)&g_r)[e];
                    float gze = ((const float*)&g_z)[e];
                    float gne = ((const float*)&g_n)[e];
                    float r = sigm_(gre + R);
                    float z = sigm_(gze + Z);
                    float n = tanhf(gne + r * (NN + bhn[c2*4 + e]));
                    float nh = (1.f - z) * n + z * hprev;
                    hsf[eseq][h] = nh;
                    short hi = f2bf(nh);
                    hsh[eseq][h] = hi;
                    hsl[eseq][h] = f2bf(nh - bf2f(hi));
                    ((float*)&onew)[e] = nh;
                }
                st4(outp + orow + hb, onew);
            }
        }
        __syncthreads();
    }
}

__global__ __launch_bounds__(256)
void final_kernel(const float* __restrict__ atom_h, const float* __restrict__ tgt_rel,
                  const int* __restrict__ srcn, const int* __restrict__ tgtn,
                  const float* __restrict__ Wl, const float* __restrict__ bl,
                  float* __restrict__ out)
{
    __shared__ float red[4];
    int b = blockIdx.x, c = threadIdx.x;
    float v = tanhf(atom_h[(size_t)srcn[b]*HD + c] + tgt_rel[b*HD + c]
                    - atom_h[(size_t)tgtn[b]*HD + c]);
    float p = v * Wl[c];
    #pragma unroll
    for (int off = 1; off < 64; off <<= 1) p += __shfl_xor(p, off);
    int wv = c >> 6;
    if ((c & 63) == 0) red[wv] = p;
    __syncthreads();
    if (c == 0) out[b] = red[0] + red[1] + red[2] + red[3] + bl[0];
}

extern "C" void kernel_launch(void* const* d_in, const int* in_sizes, int n_in,
                              void* d_out, int out_size, void* d_ws, size_t ws_size,
                              hipStream_t stream)
{
    const float* node_feat = (const float*)d_in[0];
    const float* rel_emb   = (const float*)d_in[1];
    const float* W_i_node  = (const float*)d_in[2];
    const float* W_i_edge  = (const float*)d_in[3];
    const float* Wa1       = (const float*)d_in[4];
    const float* Wa2       = (const float*)d_in[5];
    const float* W_h_atom  = (const float*)d_in[6];
    const float* W_h_bond  = (const float*)d_in[7];
    const float* Wd1       = (const float*)d_in[8];
    const float* Wd2       = (const float*)d_in[9];
    const float* W_comm    = (const float*)d_in[10];
    const float* gru_bias  = (const float*)d_in[11];
    const float* w_ih_f    = (const float*)d_in[12];
    const float* w_hh_f    = (const float*)d_in[13];
    const float* b_ih_f    = (const float*)d_in[14];
    const float* b_hh_f    = (const float*)d_in[15];
    const float* w_ih_b    = (const float*)d_in[16];
    const float* w_hh_b    = (const float*)d_in[17];
    const float* b_ih_b    = (const float*)d_in[18];
    const float* b_hh_b    = (const float*)d_in[19];
    const float* W_o       = (const float*)d_in[20];
    const float* b_o       = (const float*)d_in[21];
    const float* W_lin1    = (const float*)d_in[22];
    const float* b_lin1    = (const float*)d_in[23];
    const int* edge_src  = (const int*)d_in[24];
    const int* edge_dst  = (const int*)d_in[25];
    const int* edge_rel  = (const int*)d_in[26];
    const int* batch_rel = (const int*)d_in[27];
    const int* src_node  = (const int*)d_in[28];
    const int* tgt_node  = (const int*)d_in[29];
    float* out = (float*)d_out;

    float* ws = (float*)d_ws;
    size_t off = 0;
    auto alloc = [&](size_t n){ float* p = ws + off; off += n; return p; };
    float* tgt_rel    = alloc((size_t)Bg*HD);
    float* term       = alloc((size_t)3*Bg*HD);
    float* input_node = alloc((size_t)TNODE*HD);
    float* mn_a       = alloc((size_t)TNODE*HD);
    float* mn_b       = alloc((size_t)TNODE*HD);
    float* agg        = alloc((size_t)TNODE*HD);
    float* h0v        = alloc((size_t)Bg*HD);
    short* whbf       = (short*)alloc((size_t)2*768*256/2);
    float* bcomb      = alloc((size_t)2*768);
    float* sbuf       = alloc((size_t)TEDGE);
    int*   cnt        = (int*)alloc((size_t)TNODE);
    int*   fillc      = (int*)alloc((size_t)TNODE);
    int*   rowptr     = (int*)alloc((size_t)TNODE + 256);
    int*   eidx       = (int*)alloc((size_t)TEDGE);
    float* Sbuf       = alloc((size_t)TNODE*HD);
    float* Dbuf       = alloc((size_t)TNODE*HD);
    float* Rbuf       = alloc((size_t)256*HD);
    float* gi_f       = alloc((size_t)TNODE*768);
    float* gi_b       = alloc((size_t)TNODE*768);
    float* out_f      = alloc((size_t)TNODE*HD);
    float* out_b      = alloc((size_t)TNODE*HD);
    // aliases (lifetimes disjoint):
    float* agg2   = mn_a;        // after last attn/gather
    float* atom_h = input_node;  // after W_comm GEMM

    tgtrel_kernel<<<Bg, 256, 0, stream>>>(rel_emb, batch_rel, tgt_rel);
    whbf_kernel<<<1536, 256, 0, stream>>>(w_hh_f, w_hh_b, whbf);
    biascomb_kernel<<<6, 256, 0, stream>>>(b_ih_f, b_hh_f, b_ih_b, b_hh_b, bcomb);

    // ---- CSR build (dst-sorted incidence) ----
    zeroi_kernel<<<2*TNODE/256, 256, 0, stream>>>(cnt);     // zeros cnt AND fillc (adjacent)
    csr_count<<<TEDGE/256, 256, 0, stream>>>(edge_dst, cnt);
    csr_scan<<<1, 256, 0, stream>>>(cnt, rowptr);
    csr_fill<<<TEDGE/256, 256, 0, stream>>>(edge_dst, rowptr, fillc, eidx);

    // input_node = relu(node_feat @ W_i_node^T)
    mgemm<A_PLAIN, E_RELU><<<dim3(HD/128, TNODE/128), 256, 0, stream>>>(
        node_feat, nullptr, nullptr, W_i_node, nullptr, input_node,
        TNODE, HD, NEMB, NEMB, NEMB);

    // edge-feature factor tables: ie[e] = relu(S[src] + R[rel] + D[dst])
    mgemm<A_PLAIN, E_STORE><<<dim3(HD/128, TNODE/128), 256, 0, stream>>>(
        node_feat, nullptr, nullptr, W_i_edge + 0, nullptr, Sbuf,
        TNODE, HD, NEMB, NEMB, 512);
    mgemm<A_PLAIN, E_STORE><<<dim3(HD/128, TNODE/128), 256, 0, stream>>>(
        node_feat, nullptr, nullptr, W_i_edge + 384, nullptr, Dbuf,
        TNODE, HD, NEMB, NEMB, 512);
    mgemm<A_CLAMP, E_STORE><<<dim3(HD/128, 2), 256, 0, stream>>>(
        rel_emb, nullptr, nullptr, W_i_edge + 128, nullptr, Rbuf,
        200, HD, REMB, REMB, 512);

    term_kernel<<<3*Bg, 256, 0, stream>>>(input_node, tgt_rel, Wa1, Wd1,
                                          src_node, tgt_node, term);

    // ---- input attention scale + gather-aggregate ----
    mattn<0><<<TEDGE/64, 256, 0, stream>>>(Sbuf, Rbuf, Dbuf, Sbuf,
        edge_src, edge_rel, edge_dst, Wa1, Wa2, term, sbuf);
    agg_gather<0><<<TNODE/4, 256, 0, stream>>>(Sbuf, Rbuf, Dbuf, Sbuf,
        edge_src, edge_rel, rowptr, eidx, sbuf, agg);

    const float* mn_cur = input_node;
    float* bufs[2] = {mn_a, mn_b};
    for (int d = 0; d < 2; d++) {
        float* mn_next = bufs[d];
        float* tmp     = bufs[1-d];
        mgemm<A_ADD, E_RELU><<<dim3(2, TNODE/128), 256, 0, stream>>>(
            mn_cur, agg, nullptr, W_h_atom + (size_t)d*HD*HD, nullptr, mn_next,
            TNODE, HD, HD, HD, HD);
        mgemm<A_PLAIN, E_STORE><<<dim3(2, TNODE/128), 256, 0, stream>>>(
            mn_next, nullptr, nullptr, W_h_bond + (size_t)d*HD*HD, nullptr, tmp,
            TNODE, HD, HD, HD, HD);
        mattn<1><<<TEDGE/64, 256, 0, stream>>>(Sbuf, Rbuf, Dbuf, tmp,
            edge_src, edge_rel, edge_dst, Wd1 + (size_t)d*HD*512,
            Wd2 + (size_t)d*HD, term + (size_t)(1+d)*Bg*HD, sbuf);
        agg_gather<1><<<TNODE/4, 256, 0, stream>>>(Sbuf, Rbuf, Dbuf, tmp,
            edge_src, edge_rel, rowptr, eidx, sbuf, agg);
        mn_cur = mn_next;
    }

    // agg2 = concat([agg, mn, input_node]) @ W_comm^T   (agg2 aliases mn_a)
    mgemm<A_CAT3, E_STORE><<<dim3(2, TNODE/128), 256, 0, stream>>>(
        agg, (const float*)mn_cur, input_node, W_comm, nullptr, agg2,
        TNODE, HD, 3*HD, 0, 3*HD);

    h0_kernel<<<Bg, 256, 0, stream>>>(agg2, h0v);

    // gi = relu(agg2 + gru_bias) @ w_ih^T + (b_ih + b_hh[r,z])   (both directions)
    mgemm<A_RELUB, E_BIAS><<<dim3(768/128, TNODE/128), 256, 0, stream>>>(
        agg2, gru_bias, nullptr, w_ih_f, bcomb, gi_f,
        TNODE, 768, HD, HD, HD);
    mgemm<A_RELUB, E_BIAS><<<dim3(768/128, TNODE/128), 256, 0, stream>>>(
        agg2, gru_bias, nullptr, w_ih_b, bcomb + 768, gi_b,
        TNODE, 768, HD, HD, HD);

    gru_seq<<<16, 256, 0, stream>>>(gi_f, gi_b, whbf, b_hh_f, b_hh_b, h0v,
                                    out_f, out_b);

    // atom_h = relu(relu(concat(out_f,out_b)) @ W_o^T + b_o)
    mgemm<A_CAT2R, E_BIASRELU><<<dim3(2, TNODE/128), 256, 0, stream>>>(
        out_f, out_b, nullptr, W_o, b_o, atom_h,
        TNODE, HD, 2*HD, 0, 2*HD);

    final_kernel<<<Bg, 256, 0, stream>>>(atom_h, tgt_rel, src_node, tgt_node,
                                         W_lin1, b_lin1, out);
}

// Round 13
// 1545.253 us; speedup vs baseline: 1.1645x; 1.1645x over previous
//
#include <hip/hip_runtime.h>
#include <cstddef>

#define Bg 128
#define Nn 100
#define Eg 800
#define TNODE 12800
#define TEDGE 102400
#define HD 256
#define NEMB 128
#define REMB 256

typedef short bf8 __attribute__((ext_vector_type(8)));
typedef short bf4 __attribute__((ext_vector_type(4)));
typedef float f4  __attribute__((ext_vector_type(4)));

__device__ __forceinline__ float relu_(float x){ return x > 0.f ? x : 0.f; }
__device__ __forceinline__ float sigm_(float x){ return 1.f/(1.f + __expf(-x)); }
__device__ __forceinline__ float4 ld4(const float* p){ return *(const float4*)p; }
__device__ __forceinline__ void st4(float* p, float4 v){ *(float4*)p = v; }
__device__ __forceinline__ float4 add4(float4 a, float4 b){
    return float4{a.x+b.x, a.y+b.y, a.z+b.z, a.w+b.w};
}
__device__ __forceinline__ float4 relu4(float4 a){
    return float4{relu_(a.x), relu_(a.y), relu_(a.z), relu_(a.w)};
}
__device__ __forceinline__ short f2bf(float f){
    unsigned u = __float_as_uint(f);
    u += 0x7fff + ((u >> 16) & 1);
    return (short)(u >> 16);
}
__device__ __forceinline__ float bf2f(short s){
    return __uint_as_float(((unsigned)(unsigned short)s) << 16);
}
__device__ __forceinline__ void split4(float4 v, bf4& h, bf4& l){
    h.x = f2bf(v.x); l.x = f2bf(v.x - bf2f(h.x));
    h.y = f2bf(v.y); l.y = f2bf(v.y - bf2f(h.y));
    h.z = f2bf(v.z); l.z = f2bf(v.z - bf2f(h.z));
    h.w = f2bf(v.w); l.w = f2bf(v.w - bf2f(h.w));
}
__device__ __forceinline__ f4 mfma_(bf8 a, bf8 b, f4 c){
    return __builtin_amdgcn_mfma_f32_16x16x32_bf16(a, b, c, 0, 0, 0);
}

enum { A_PLAIN=0, A_ADD=1, A_RELUB=2, A_CLAMP=3, A_CAT3=4, A_CAT2R=5 };
enum { E_STORE=0, E_RELU=1, E_BIAS=2, E_BIASRELU=3 };

// ---------- MFMA split-bf16 GEMM: C[M,N] = epi(A[M,K] @ W[N,K]^T), ~f32 accuracy ----------
template<int AM, int EM>
__global__ __launch_bounds__(256, 2)
void mgemm(const float* __restrict__ A0, const float* __restrict__ A1,
           const float* __restrict__ A2, const float* __restrict__ W,
           const float* __restrict__ bias, float* __restrict__ C,
           int M, int N, int K, int lda, int wld)
{
    __shared__ short Ah[128][40], Al[128][40], Bh[128][40], Bl[128][40];
    const int t  = threadIdx.x;
    const int kc = t & 7, lr = t >> 3;
    const int lane = t & 63, wv = t >> 6;
    const int wm = wv >> 1, wn = wv & 1;
    const int frow = lane & 15, fk = (lane >> 4) * 8;
    const int row0 = blockIdx.y * 128, col0 = blockIdx.x * 128;

    f4 acc[4][4] = {};

    for (int k0 = 0; k0 < K; k0 += 32) {
        const int gk = k0 + kc * 4;
        const int kk = kc * 4;
        #pragma unroll
        for (int ri = 0; ri < 4; ri++) {
            int row = lr + 32 * ri;
            int grow = row0 + row;
            float4 v;
            if (AM == A_PLAIN) {
                v = ld4(A0 + (size_t)grow * lda + gk);
            } else if (AM == A_ADD) {
                v = add4(ld4(A0 + (size_t)grow * lda + gk),
                         ld4(A1 + (size_t)grow * lda + gk));
            } else if (AM == A_RELUB) {
                v = relu4(add4(ld4(A0 + (size_t)grow * lda + gk), ld4(A1 + gk)));
            } else if (AM == A_CLAMP) {
                int cr = grow < M ? grow : M - 1;
                v = ld4(A0 + (size_t)cr * lda + gk);
            } else if (AM == A_CAT3) {
                if (gk < HD)        v = ld4(A0 + (size_t)grow * HD + gk);
                else if (gk < 2*HD) v = ld4(A1 + (size_t)grow * HD + gk - HD);
                else                v = ld4(A2 + (size_t)grow * HD + gk - 2*HD);
            } else { // A_CAT2R
                v = (gk < HD) ? relu4(ld4(A0 + (size_t)grow * HD + gk))
                              : relu4(ld4(A1 + (size_t)grow * HD + gk - HD));
            }
            bf4 h, l; split4(v, h, l);
            *(bf4*)&Ah[row][kk] = h;
            *(bf4*)&Al[row][kk] = l;
        }
        #pragma unroll
        for (int ri = 0; ri < 4; ri++) {
            int wr = lr + 32 * ri;
            float4 v = ld4(W + (size_t)(col0 + wr) * wld + gk);
            bf4 h, l; split4(v, h, l);
            *(bf4*)&Bh[wr][kk] = h;
            *(bf4*)&Bl[wr][kk] = l;
        }
        __syncthreads();
        bf8 ah[4], al[4], bh[4], bl[4];
        #pragma unroll
        for (int mi = 0; mi < 4; mi++) {
            ah[mi] = *(const bf8*)&Ah[wm*64 + mi*16 + frow][fk];
            al[mi] = *(const bf8*)&Al[wm*64 + mi*16 + frow][fk];
        }
        #pragma unroll
        for (int ni = 0; ni < 4; ni++) {
            bh[ni] = *(const bf8*)&Bh[wn*64 + ni*16 + frow][fk];
            bl[ni] = *(const bf8*)&Bl[wn*64 + ni*16 + frow][fk];
        }
        #pragma unroll
        for (int mi = 0; mi < 4; mi++)
            #pragma unroll
            for (int ni = 0; ni < 4; ni++) {
                acc[mi][ni] = mfma_(ah[mi], bh[ni], acc[mi][ni]);
                acc[mi][ni] = mfma_(ah[mi], bl[ni], acc[mi][ni]);
                acc[mi][ni] = mfma_(al[mi], bh[ni], acc[mi][ni]);
            }
        __syncthreads();
    }
    #pragma unroll
    for (int mi = 0; mi < 4; mi++) {
        #pragma unroll
        for (int ni = 0; ni < 4; ni++) {
            int ccol = col0 + wn*64 + ni*16 + frow;
            int rbase = row0 + wm*64 + mi*16 + (lane >> 4) * 4;
            #pragma unroll
            for (int reg = 0; reg < 4; reg++) {
                float v = acc[mi][ni][reg];
                if (EM == E_BIAS || EM == E_BIASRELU) v += bias[ccol];
                if (EM == E_RELU || EM == E_BIASRELU) v = relu_(v);
                C[(size_t)(rbase + reg) * N + ccol] = v;
            }
        }
    }
}

// ---------- MFMA attention over reconstructed edge features ----------
template<int MODE>
__global__ __launch_bounds__(256, 2)
void mattn(const float* __restrict__ S, const float* __restrict__ Rt,
           const float* __restrict__ D, const float* __restrict__ T0,
           const int* __restrict__ esrc, const int* __restrict__ erel,
           const int* __restrict__ edst,
           const float* __restrict__ W1, const float* __restrict__ W2,
           const float* __restrict__ term, float* __restrict__ sbuf)
{
    __shared__ short Ah[64][40], Al[64][40], Bh[256][40], Bl[256][40];
    __shared__ float partl[4][64];
    __shared__ int isrc[64], irel[64], idst[64];
    const int t = threadIdx.x;
    const int kc = t & 7, lr = t >> 3;
    const int lane = t & 63, wv = t >> 6;
    const int frow = lane & 15, fk = (lane >> 4) * 8;
    const int r0 = blockIdx.x * 64;

    if (t < 64) {
        int e = r0 + t;
        isrc[t] = esrc[e]; irel[t] = erel[e]; idst[t] = edst[e];
    }
    __syncthreads();

    f4 acc[4][4] = {};

    for (int k0 = 0; k0 < HD; k0 += 32) {
        const int gk = k0 + kc * 4;
        const int kk = kc * 4;
        #pragma unroll
        for (int ri = 0; ri < 2; ri++) {
            int row = lr + 32 * ri;
            int s = isrc[row], rl = irel[row], dd = idst[row];
            float4 v = relu4(add4(add4(ld4(S + (size_t)s * HD + gk),
                                       ld4(Rt + (size_t)rl * HD + gk)),
                                  ld4(D + (size_t)dd * HD + gk)));
            if (MODE) v = relu4(add4(v, ld4(T0 + (size_t)s * HD + gk)));
            bf4 h, l; split4(v, h, l);
            *(bf4*)&Ah[row][kk] = h;
            *(bf4*)&Al[row][kk] = l;
        }
        #pragma unroll
        for (int ri = 0; ri < 8; ri++) {
            int wr = lr + 32 * ri;
            float4 v = ld4(W1 + (size_t)wr * 512 + gk);   // left half of [256,512]
            bf4 h, l; split4(v, h, l);
            *(bf4*)&Bh[wr][kk] = h;
            *(bf4*)&Bl[wr][kk] = l;
        }
        __syncthreads();
        bf8 ah[4], al[4], bh[4], bl[4];
        #pragma unroll
        for (int mi = 0; mi < 4; mi++) {
            ah[mi] = *(const bf8*)&Ah[mi*16 + frow][fk];
            al[mi] = *(const bf8*)&Al[mi*16 + frow][fk];
        }
        #pragma unroll
        for (int ni = 0; ni < 4; ni++) {
            bh[ni] = *(const bf8*)&Bh[wv*64 + ni*16 + frow][fk];
            bl[ni] = *(const bf8*)&Bl[wv*64 + ni*16 + frow][fk];
        }
        #pragma unroll
        for (int mi = 0; mi < 4; mi++)
            #pragma unroll
            for (int ni = 0; ni < 4; ni++) {
                acc[mi][ni] = mfma_(ah[mi], bh[ni], acc[mi][ni]);
                acc[mi][ni] = mfma_(ah[mi], bl[ni], acc[mi][ni]);
                acc[mi][ni] = mfma_(al[mi], bh[ni], acc[mi][ni]);
            }
        __syncthreads();
    }
    #pragma unroll
    for (int mi = 0; mi < 4; mi++) {
        #pragma unroll
        for (int reg = 0; reg < 4; reg++) {
            int rl = mi*16 + (lane >> 4) * 4 + reg;
            int g = (r0 + rl) / Eg;
            float p = 0.f;
            #pragma unroll
            for (int ni = 0; ni < 4; ni++) {
                int n = wv*64 + ni*16 + frow;
                p += tanhf(acc[mi][ni][reg] + term[g*HD + n]) * W2[n];
            }
            p += __shfl_xor(p, 1); p += __shfl_xor(p, 2);
            p += __shfl_xor(p, 4); p += __shfl_xor(p, 8);
            if (frow == 0) partl[wv][rl] = p;
        }
    }
    __syncthreads();
    if (t < 64) {
        float p = partl[0][t] + partl[1][t] + partl[2][t] + partl[3][t];
        sbuf[r0 + t] = sigm_(p);
    }
}

// ------- CSR-gather aggregation: agg[n] = sum_{e: dst[e]==n} me(e) * s[e] -------
template<int MODE>
__global__ __launch_bounds__(256)
void agg_gather(const float* __restrict__ S, const float* __restrict__ Rt,
                const float* __restrict__ D, const float* __restrict__ T0,
                const int* __restrict__ esrc, const int* __restrict__ erel,
                const int* __restrict__ rowptr, const int* __restrict__ eidx,
                const float* __restrict__ s, float* __restrict__ agg)
{
    int node = blockIdx.x * 4 + (threadIdx.x >> 6);
    int c = (threadIdx.x & 63) * 4;
    float4 dn = ld4(D + (size_t)node * HD + c);   // dst row constant per node
    float4 acc{0.f, 0.f, 0.f, 0.f};
    int beg = rowptr[node], end = rowptr[node + 1];
    for (int i = beg; i < end; i++) {
        int e = eidx[i];
        int sr = esrc[e], rl = erel[e];
        float4 v = relu4(add4(add4(ld4(S + (size_t)sr * HD + c),
                                   ld4(Rt + (size_t)rl * HD + c)), dn));
        if (MODE) v = relu4(add4(v, ld4(T0 + (size_t)sr * HD + c)));
        float sc = s[e];
        acc.x += v.x * sc; acc.y += v.y * sc;
        acc.z += v.z * sc; acc.w += v.w * sc;
    }
    st4(agg + (size_t)node * HD + c, acc);
}

// ------------- CSR build -------------
__global__ void zeroi_kernel(int* __restrict__ p)
{
    p[blockIdx.x * 256 + threadIdx.x] = 0;
}
__global__ void csr_count(const int* __restrict__ dst, int* __restrict__ cnt)
{
    int e = blockIdx.x * 256 + threadIdx.x;
    atomicAdd(&cnt[dst[e]], 1);
}
__global__ void csr_scan(const int* __restrict__ cnt, int* __restrict__ rowptr)
{
    __shared__ int ws[4];
    __shared__ int carry;
    int tid = threadIdx.x;
    if (tid == 0) carry = 0;
    __syncthreads();
    for (int i = 0; i < TNODE; i += 256) {
        int v = cnt[i + tid];
        int x = v;
        #pragma unroll
        for (int off = 1; off < 64; off <<= 1) {
            int y = __shfl_up(x, off);
            if ((tid & 63) >= off) x += y;
        }
        if ((tid & 63) == 63) ws[tid >> 6] = x;
        __syncthreads();
        int add = carry;
        int w = tid >> 6;
        for (int j = 0; j < w; j++) add += ws[j];
        rowptr[i + tid] = add + x - v;      // exclusive
        __syncthreads();
        if (tid == 255) carry = add + x;
        __syncthreads();
    }
    if (tid == 0) rowptr[TNODE] = carry;
}
__global__ void csr_fill(const int* __restrict__ dst, const int* __restrict__ rowptr,
                         int* __restrict__ fillc, int* __restrict__ eidx)
{
    int e = blockIdx.x * 256 + threadIdx.x;
    int d = dst[e];
    int slot = rowptr[d] + atomicAdd(&fillc[d], 1);
    eidx[slot] = e;
}

// ------------- per-graph attention bias terms -------------
__global__ __launch_bounds__(256)
void term_kernel(const float* __restrict__ mn, const float* __restrict__ tgt_rel,
                 const float* __restrict__ Wa1, const float* __restrict__ Wd1,
                 const int* __restrict__ srcn, const int* __restrict__ tgtn,
                 float* __restrict__ term)
{
    __shared__ float Gs[HD];
    int b = blockIdx.x % Bg;
    int which = blockIdx.x / Bg;
    int c = threadIdx.x;
    float g;
    if (which == 0)
        g = mn[(size_t)srcn[b]*HD + c] + tgt_rel[b*HD + c] - mn[(size_t)tgtn[b]*HD + c];
    else
        g = tgt_rel[b*HD + c];
    Gs[c] = g;
    __syncthreads();
    const float* W = (which == 0) ? Wa1 : (Wd1 + (size_t)(which-1)*HD*512);
    float p = 0.f;
    for (int k = 0; k < HD; k += 4) {
        float4 w = ld4(W + (size_t)c*512 + 256 + k);
        p = fmaf(Gs[k], w.x, p); p = fmaf(Gs[k+1], w.y, p);
        p = fmaf(Gs[k+2], w.z, p); p = fmaf(Gs[k+3], w.w, p);
    }
    term[(size_t)which*Bg*HD + b*HD + c] = p;
}

__global__ void tgtrel_kernel(const float* __restrict__ rel_emb, const int* __restrict__ batch_rel,
                              float* __restrict__ tgt_rel)
{
    int b = blockIdx.x, c = threadIdx.x;
    tgt_rel[b*HD + c] = rel_emb[(size_t)batch_rel[b]*REMB + c];
}

__global__ void h0_kernel(const float* __restrict__ agg2, float* __restrict__ h0)
{
    int b = blockIdx.x, c = threadIdx.x;
    float m = -1e30f;
    for (int n = 0; n < Nn; n++)
        m = fmaxf(m, agg2[((size_t)b*Nn + n)*HD + c]);
    h0[b*HD + c] = m;
}

// ------------- convert w_hh to bf16: whbf[d][row][k] -------------
__global__ void whbf_kernel(const float* __restrict__ whf, const float* __restrict__ whb,
                            short* __restrict__ whbf)
{
    int idx = blockIdx.x * 256 + threadIdx.x;   // 2*768*256
    int d = idx / (768*256), rem = idx % (768*256);
    whbf[idx] = f2bf((d ? whb : whf)[rem]);
}

// ------------- combined gi bias: bc[d] = b_ih + (r,z part of b_hh) -------------
__global__ void biascomb_kernel(const float* __restrict__ bihf, const float* __restrict__ bhhf,
                                const float* __restrict__ bihb, const float* __restrict__ bhhb,
                                float* __restrict__ bc)
{
    int i = blockIdx.x * 256 + threadIdx.x;   // 1536
    int d = i / 768, r = i % 768;
    const float* bi = d ? bihb : bihf;
    const float* bhh = d ? bhhb : bhhf;
    bc[i] = bi[r] + (r < 512 ? bhh[r] : 0.f);
}

// ------------- GRU: 16 blocks x 512 thr (8 waves); HALF weight panel VGPR-resident -------------
// Wave owns 6 n-tiles: tiles 0-2 resident (96 VGPRs, loaded once, fits 256-reg cap),
// tiles 3-5 streamed from L2 (196 KB/step, half of round-11). gi prefetched before MFMA.
__global__ __launch_bounds__(512, 2)
void gru_seq(const float* __restrict__ gi_f, const float* __restrict__ gi_b,
             const short* __restrict__ whbf,
             const float* __restrict__ bhf, const float* __restrict__ bhb,
             const float* __restrict__ h0,
             float* __restrict__ outf, float* __restrict__ outb)
{
    __shared__ float hsf[16][260];      // h state f32
    __shared__ short hsh[16][264];      // h bf16 hi
    __shared__ short hsl[16][264];      // h bf16 lo
    __shared__ float gates[768][17];    // [gate*256+h][seq]
    const int blk = blockIdx.x;         // dir*8 + grp
    const int d = blk >> 3, grp = blk & 7;
    const int tid = threadIdx.x;
    const int lane = tid & 63, wv = tid >> 6;   // 8 waves
    const int f16 = lane & 15;
    const int kb  = (lane >> 4) * 8;

    const short* wp0 = whbf + (size_t)d * 768 * 256;
    const float* gi  = d ? gi_b : gi_f;
    const float* bh  = d ? bhb : bhf;
    float* outp      = d ? outb : outf;

    // ---- resident weights: tiles 0..2 of this wave's 6 ----
    bf8 wregA[3][8];
    #pragma unroll
    for (int j = 0; j < 3; j++) {
        int wr = (wv*6 + j) * 16 + f16;
        const short* wp = wp0 + (size_t)wr * 256 + kb;
        #pragma unroll
        for (int ks = 0; ks < 8; ks++)
            wregA[j][ks] = *(const bf8*)(wp + ks*32);
    }

    const int eseq = tid >> 5, ehb = tid & 31;      // epilogue: 8 h per thread
    float bhn[8];
    #pragma unroll
    for (int hh = 0; hh < 8; hh++) bhn[hh] = bh[512 + ehb + hh * 32];

    {   // init h
        #pragma unroll
        for (int hh = 0; hh < 8; hh++) {
            int h = ehb + hh * 32;
            float v = h0[(size_t)(grp*16 + eseq) * HD + h];
            hsf[eseq][h] = v;
            short hi = f2bf(v);
            hsh[eseq][h] = hi;
            hsl[eseq][h] = f2bf(v - bf2f(hi));
        }
    }
    __syncthreads();

    for (int t = 0; t < Nn; t++) {
        int trow = d ? (Nn - 1 - t) : t;
        // --- gi prefetch (hides HBM latency under MFMA phase) ---
        float gr[8], gz[8], gn[8];
        {
            size_t girow = ((size_t)(grp*16 + eseq) * Nn + trow) * 768;
            #pragma unroll
            for (int hh = 0; hh < 8; hh++) {
                int h = ehb + hh * 32;
                gr[hh] = gi[girow + h];
                gz[hh] = gi[girow + 256 + h];
                gn[hh] = gi[girow + 512 + h];
            }
        }
        // --- MFMA: tiles 0-2 from registers, tiles 3-5 streamed ---
        #pragma unroll
        for (int j = 0; j < 6; j++) {
            const short* wp = wp0 + (size_t)((wv*6 + j) * 16 + f16) * 256 + kb;
            f4 acc = {};
            #pragma unroll
            for (int ks = 0; ks < 8; ks++) {
                bf8 ahi = *(const bf8*)&hsh[f16][ks*32 + kb];
                bf8 alo = *(const bf8*)&hsl[f16][ks*32 + kb];
                bf8 b = (j < 3) ? wregA[j][ks] : *(const bf8*)(wp + ks*32);
                acc = mfma_(ahi, b, acc);
                acc = mfma_(alo, b, acc);
            }
            #pragma unroll
            for (int reg = 0; reg < 4; reg++)
                gates[(wv*6 + j)*16 + f16][(lane >> 4)*4 + reg] = acc[reg];
        }
        __syncthreads();
        // --- epilogue: thread owns (eseq, ehb + hh*32); gi already includes b_hh r/z ---
        {
            size_t orow = ((size_t)(grp*16 + eseq) * Nn + trow) * HD;
            #pragma unroll
            for (int hh = 0; hh < 8; hh++) {
                int h = ehb + hh * 32;
                float R  = gates[h][eseq];
                float Z  = gates[256 + h][eseq];
                float NN = gates[512 + h][eseq];
                float hprev = hsf[eseq][h];
                float r = sigm_(gr[hh] + R);
                float z = sigm_(gz[hh] + Z);
                float n = tanhf(gn[hh] + r * (NN + bhn[hh]));
                float nh = (1.f - z) * n + z * hprev;
                hsf[eseq][h] = nh;
                short hi = f2bf(nh);
                hsh[eseq][h] = hi;
                hsl[eseq][h] = f2bf(nh - bf2f(hi));
                outp[orow + h] = nh;
            }
        }
        __syncthreads();
    }
}

__global__ __launch_bounds__(256)
void final_kernel(const float* __restrict__ atom_h, const float* __restrict__ tgt_rel,
                  const int* __restrict__ srcn, const int* __restrict__ tgtn,
                  const float* __restrict__ Wl, const float* __restrict__ bl,
                  float* __restrict__ out)
{
    __shared__ float red[4];
    int b = blockIdx.x, c = threadIdx.x;
    float v = tanhf(atom_h[(size_t)srcn[b]*HD + c] + tgt_rel[b*HD + c]
                    - atom_h[(size_t)tgtn[b]*HD + c]);
    float p = v * Wl[c];
    #pragma unroll
    for (int off = 1; off < 64; off <<= 1) p += __shfl_xor(p, off);
    int wv = c >> 6;
    if ((c & 63) == 0) red[wv] = p;
    __syncthreads();
    if (c == 0) out[b] = red[0] + red[1] + red[2] + red[3] + bl[0];
}

extern "C" void kernel_launch(void* const* d_in, const int* in_sizes, int n_in,
                              void* d_out, int out_size, void* d_ws, size_t ws_size,
                              hipStream_t stream)
{
    const float* node_feat = (const float*)d_in[0];
    const float* rel_emb   = (const float*)d_in[1];
    const float* W_i_node  = (const float*)d_in[2];
    const float* W_i_edge  = (const float*)d_in[3];
    const float* Wa1       = (const float*)d_in[4];
    const float* Wa2       = (const float*)d_in[5];
    const float* W_h_atom  = (const float*)d_in[6];
    const float* W_h_bond  = (const float*)d_in[7];
    const float* Wd1       = (const float*)d_in[8];
    const float* Wd2       = (const float*)d_in[9];
    const float* W_comm    = (const float*)d_in[10];
    const float* gru_bias  = (const float*)d_in[11];
    const float* w_ih_f    = (const float*)d_in[12];
    const float* w_hh_f    = (const float*)d_in[13];
    const float* b_ih_f    = (const float*)d_in[14];
    const float* b_hh_f    = (const float*)d_in[15];
    const float* w_ih_b    = (const float*)d_in[16];
    const float* w_hh_b    = (const float*)d_in[17];
    const float* b_ih_b    = (const float*)d_in[18];
    const float* b_hh_b    = (const float*)d_in[19];
    const float* W_o       = (const float*)d_in[20];
    const float* b_o       = (const float*)d_in[21];
    const float* W_lin1    = (const float*)d_in[22];
    const float* b_lin1    = (const float*)d_in[23];
    const int* edge_src  = (const int*)d_in[24];
    const int* edge_dst  = (const int*)d_in[25];
    const int* edge_rel  = (const int*)d_in[26];
    const int* batch_rel = (const int*)d_in[27];
    const int* src_node  = (const int*)d_in[28];
    const int* tgt_node  = (const int*)d_in[29];
    float* out = (float*)d_out;

    float* ws = (float*)d_ws;
    size_t off = 0;
    auto alloc = [&](size_t n){ float* p = ws + off; off += n; return p; };
    float* tgt_rel    = alloc((size_t)Bg*HD);
    float* term       = alloc((size_t)3*Bg*HD);
    float* input_node = alloc((size_t)TNODE*HD);
    float* mn_a       = alloc((size_t)TNODE*HD);
    float* mn_b       = alloc((size_t)TNODE*HD);
    float* agg        = alloc((size_t)TNODE*HD);
    float* h0v        = alloc((size_t)Bg*HD);
    short* whbf       = (short*)alloc((size_t)2*768*256/2);
    float* bcomb      = alloc((size_t)2*768);
    float* sbuf       = alloc((size_t)TEDGE);
    int*   cnt        = (int*)alloc((size_t)TNODE);
    int*   fillc      = (int*)alloc((size_t)TNODE);
    int*   rowptr     = (int*)alloc((size_t)TNODE + 256);
    int*   eidx       = (int*)alloc((size_t)TEDGE);
    float* Sbuf       = alloc((size_t)TNODE*HD);
    float* Dbuf       = alloc((size_t)TNODE*HD);
    float* Rbuf       = alloc((size_t)256*HD);
    float* gi_f       = alloc((size_t)TNODE*768);
    float* gi_b       = alloc((size_t)TNODE*768);
    float* out_f      = alloc((size_t)TNODE*HD);
    float* out_b      = alloc((size_t)TNODE*HD);
    // aliases (lifetimes disjoint):
    float* agg2   = mn_a;        // after last attn/gather
    float* atom_h = input_node;  // after W_comm GEMM

    tgtrel_kernel<<<Bg, 256, 0, stream>>>(rel_emb, batch_rel, tgt_rel);
    whbf_kernel<<<1536, 256, 0, stream>>>(w_hh_f, w_hh_b, whbf);
    biascomb_kernel<<<6, 256, 0, stream>>>(b_ih_f, b_hh_f, b_ih_b, b_hh_b, bcomb);

    // ---- CSR build (dst-sorted incidence) ----
    zeroi_kernel<<<2*TNODE/256, 256, 0, stream>>>(cnt);     // zeros cnt AND fillc (adjacent)
    csr_count<<<TEDGE/256, 256, 0, stream>>>(edge_dst, cnt);
    csr_scan<<<1, 256, 0, stream>>>(cnt, rowptr);
    csr_fill<<<TEDGE/256, 256, 0, stream>>>(edge_dst, rowptr, fillc, eidx);

    // input_node = relu(node_feat @ W_i_node^T)
    mgemm<A_PLAIN, E_RELU><<<dim3(HD/128, TNODE/128), 256, 0, stream>>>(
        node_feat, nullptr, nullptr, W_i_node, nullptr, input_node,
        TNODE, HD, NEMB, NEMB, NEMB);

    // edge-feature factor tables: ie[e] = relu(S[src] + R[rel] + D[dst])
    mgemm<A_PLAIN, E_STORE><<<dim3(HD/128, TNODE/128), 256, 0, stream>>>(
        node_feat, nullptr, nullptr, W_i_edge + 0, nullptr, Sbuf,
        TNODE, HD, NEMB, NEMB, 512);
    mgemm<A_PLAIN, E_STORE><<<dim3(HD/128, TNODE/128), 256, 0, stream>>>(
        node_feat, nullptr, nullptr, W_i_edge + 384, nullptr, Dbuf,
        TNODE, HD, NEMB, NEMB, 512);
    mgemm<A_CLAMP, E_STORE><<<dim3(HD/128, 2), 256, 0, stream>>>(
        rel_emb, nullptr, nullptr, W_i_edge + 128, nullptr, Rbuf,
        200, HD, REMB, REMB, 512);

    term_kernel<<<3*Bg, 256, 0, stream>>>(input_node, tgt_rel, Wa1, Wd1,
                                          src_node, tgt_node, term);

    // ---- input attention scale + gather-aggregate ----
    mattn<0><<<TEDGE/64, 256, 0, stream>>>(Sbuf, Rbuf, Dbuf, Sbuf,
        edge_src, edge_rel, edge_dst, Wa1, Wa2, term, sbuf);
    agg_gather<0><<<TNODE/4, 256, 0, stream>>>(Sbuf, Rbuf, Dbuf, Sbuf,
        edge_src, edge_rel, rowptr, eidx, sbuf, agg);

    const float* mn_cur = input_node;
    float* bufs[2] = {mn_a, mn_b};
    for (int d = 0; d < 2; d++) {
        float* mn_next = bufs[d];
        float* tmp     = bufs[1-d];
        mgemm<A_ADD, E_RELU><<<dim3(2, TNODE/128), 256, 0, stream>>>(
            mn_cur, agg, nullptr, W_h_atom + (size_t)d*HD*HD, nullptr, mn_next,
            TNODE, HD, HD, HD, HD);
        mgemm<A_PLAIN, E_STORE><<<dim3(2, TNODE/128), 256, 0, stream>>>(
            mn_next, nullptr, nullptr, W_h_bond + (size_t)d*HD*HD, nullptr, tmp,
            TNODE, HD, HD, HD, HD);
        mattn<1><<<TEDGE/64, 256, 0, stream>>>(Sbuf, Rbuf, Dbuf, tmp,
            edge_src, edge_rel, edge_dst, Wd1 + (size_t)d*HD*512,
            Wd2 + (size_t)d*HD, term + (size_t)(1+d)*Bg*HD, sbuf);
        agg_gather<1><<<TNODE/4, 256, 0, stream>>>(Sbuf, Rbuf, Dbuf, tmp,
            edge_src, edge_rel, rowptr, eidx, sbuf, agg);
        mn_cur = mn_next;
    }

    // agg2 = concat([agg, mn, input_node]) @ W_comm^T   (agg2 aliases mn_a)
    mgemm<A_CAT3, E_STORE><<<dim3(2, TNODE/128), 256, 0, stream>>>(
        agg, (const float*)mn_cur, input_node, W_comm, nullptr, agg2,
        TNODE, HD, 3*HD, 0, 3*HD);

    h0_kernel<<<Bg, 256, 0, stream>>>(agg2, h0v);

    // gi = relu(agg2 + gru_bias) @ w_ih^T + (b_ih + b_hh[r,z])   (both directions)
    mgemm<A_RELUB, E_BIAS><<<dim3(768/128, TNODE/128), 256, 0, stream>>>(
        agg2, gru_bias, nullptr, w_ih_f, bcomb, gi_f,
        TNODE, 768, HD, HD, HD);
    mgemm<A_RELUB, E_BIAS><<<dim3(768/128, TNODE/128), 256, 0, stream>>>(
        agg2, gru_bias, nullptr, w_ih_b, bcomb + 768, gi_b,
        TNODE, 768, HD, HD, HD);

    gru_seq<<<16, 512, 0, stream>>>(gi_f, gi_b, whbf, b_hh_f, b_hh_b, h0v,
                                    out_f, out_b);

    // atom_h = relu(relu(concat(out_f,out_b)) @ W_o^T + b_o)
    mgemm<A_CAT2R, E_BIASRELU><<<dim3(2, TNODE/128), 256, 0, stream>>>(
        out_f, out_b, nullptr, W_o, b_o, atom_h,
        TNODE, HD, 2*HD, 0, 2*HD);

    final_kernel<<<Bg, 256, 0, stream>>>(atom_h, tgt_rel, src_node, tgt_node,
                                         W_lin1, b_lin1, out);
}

// Round 14
// 1319.126 us; speedup vs baseline: 1.3641x; 1.1714x over previous
//
#include <hip/hip_runtime.h>
#include <cstddef>

#define Bg 128
#define Nn 100
#define Eg 800
#define TNODE 12800
#define TEDGE 102400
#define HD 256
#define NEMB 128
#define REMB 256

typedef short bf8 __attribute__((ext_vector_type(8)));
typedef short bf4 __attribute__((ext_vector_type(4)));
typedef float f4  __attribute__((ext_vector_type(4)));

__device__ __forceinline__ float relu_(float x){ return x > 0.f ? x : 0.f; }
__device__ __forceinline__ float sigm_(float x){ return 1.f/(1.f + __expf(-x)); }
__device__ __forceinline__ float4 ld4(const float* p){ return *(const float4*)p; }
__device__ __forceinline__ void st4(float* p, float4 v){ *(float4*)p = v; }
__device__ __forceinline__ float4 add4(float4 a, float4 b){
    return float4{a.x+b.x, a.y+b.y, a.z+b.z, a.w+b.w};
}
__device__ __forceinline__ float4 relu4(float4 a){
    return float4{relu_(a.x), relu_(a.y), relu_(a.z), relu_(a.w)};
}
__device__ __forceinline__ short f2bf(float f){
    unsigned u = __float_as_uint(f);
    u += 0x7fff + ((u >> 16) & 1);
    return (short)(u >> 16);
}
__device__ __forceinline__ float bf2f(short s){
    return __uint_as_float(((unsigned)(unsigned short)s) << 16);
}
__device__ __forceinline__ void split4(float4 v, bf4& h, bf4& l){
    h.x = f2bf(v.x); l.x = f2bf(v.x - bf2f(h.x));
    h.y = f2bf(v.y); l.y = f2bf(v.y - bf2f(h.y));
    h.z = f2bf(v.z); l.z = f2bf(v.z - bf2f(h.z));
    h.w = f2bf(v.w); l.w = f2bf(v.w - bf2f(h.w));
}
__device__ __forceinline__ f4 mfma_(bf8 a, bf8 b, f4 c){
    return __builtin_amdgcn_mfma_f32_16x16x32_bf16(a, b, c, 0, 0, 0);
}

enum { A_PLAIN=0, A_ADD=1, A_RELUB=2, A_CLAMP=3, A_CAT3=4, A_CAT2R=5 };
enum { E_STORE=0, E_RELU=1, E_BIAS=2, E_BIASRELU=3 };

// ---------- MFMA split-bf16 GEMM: C[M,N] = epi(A[M,K] @ W[N,K]^T), ~f32 accuracy ----------
template<int AM, int EM>
__global__ __launch_bounds__(256, 2)
void mgemm(const float* __restrict__ A0, const float* __restrict__ A1,
           const float* __restrict__ A2, const float* __restrict__ W,
           const float* __restrict__ bias, float* __restrict__ C,
           int M, int N, int K, int lda, int wld)
{
    __shared__ short Ah[128][40], Al[128][40], Bh[128][40], Bl[128][40];
    const int t  = threadIdx.x;
    const int kc = t & 7, lr = t >> 3;
    const int lane = t & 63, wv = t >> 6;
    const int wm = wv >> 1, wn = wv & 1;
    const int frow = lane & 15, fk = (lane >> 4) * 8;
    const int row0 = blockIdx.y * 128, col0 = blockIdx.x * 128;

    f4 acc[4][4] = {};

    for (int k0 = 0; k0 < K; k0 += 32) {
        const int gk = k0 + kc * 4;
        const int kk = kc * 4;
        #pragma unroll
        for (int ri = 0; ri < 4; ri++) {
            int row = lr + 32 * ri;
            int grow = row0 + row;
            float4 v;
            if (AM == A_PLAIN) {
                v = ld4(A0 + (size_t)grow * lda + gk);
            } else if (AM == A_ADD) {
                v = add4(ld4(A0 + (size_t)grow * lda + gk),
                         ld4(A1 + (size_t)grow * lda + gk));
            } else if (AM == A_RELUB) {
                v = relu4(add4(ld4(A0 + (size_t)grow * lda + gk), ld4(A1 + gk)));
            } else if (AM == A_CLAMP) {
                int cr = grow < M ? grow : M - 1;
                v = ld4(A0 + (size_t)cr * lda + gk);
            } else if (AM == A_CAT3) {
                if (gk < HD)        v = ld4(A0 + (size_t)grow * HD + gk);
                else if (gk < 2*HD) v = ld4(A1 + (size_t)grow * HD + gk - HD);
                else                v = ld4(A2 + (size_t)grow * HD + gk - 2*HD);
            } else { // A_CAT2R
                v = (gk < HD) ? relu4(ld4(A0 + (size_t)grow * HD + gk))
                              : relu4(ld4(A1 + (size_t)grow * HD + gk - HD));
            }
            bf4 h, l; split4(v, h, l);
            *(bf4*)&Ah[row][kk] = h;
            *(bf4*)&Al[row][kk] = l;
        }
        #pragma unroll
        for (int ri = 0; ri < 4; ri++) {
            int wr = lr + 32 * ri;
            float4 v = ld4(W + (size_t)(col0 + wr) * wld + gk);
            bf4 h, l; split4(v, h, l);
            *(bf4*)&Bh[wr][kk] = h;
            *(bf4*)&Bl[wr][kk] = l;
        }
        __syncthreads();
        bf8 ah[4], al[4], bh[4], bl[4];
        #pragma unroll
        for (int mi = 0; mi < 4; mi++) {
            ah[mi] = *(const bf8*)&Ah[wm*64 + mi*16 + frow][fk];
            al[mi] = *(const bf8*)&Al[wm*64 + mi*16 + frow][fk];
        }
        #pragma unroll
        for (int ni = 0; ni < 4; ni++) {
            bh[ni] = *(const bf8*)&Bh[wn*64 + ni*16 + frow][fk];
            bl[ni] = *(const bf8*)&Bl[wn*64 + ni*16 + frow][fk];
        }
        #pragma unroll
        for (int mi = 0; mi < 4; mi++)
            #pragma unroll
            for (int ni = 0; ni < 4; ni++) {
                acc[mi][ni] = mfma_(ah[mi], bh[ni], acc[mi][ni]);
                acc[mi][ni] = mfma_(ah[mi], bl[ni], acc[mi][ni]);
                acc[mi][ni] = mfma_(al[mi], bh[ni], acc[mi][ni]);
            }
        __syncthreads();
    }
    #pragma unroll
    for (int mi = 0; mi < 4; mi++) {
        #pragma unroll
        for (int ni = 0; ni < 4; ni++) {
            int ccol = col0 + wn*64 + ni*16 + frow;
            int rbase = row0 + wm*64 + mi*16 + (lane >> 4) * 4;
            #pragma unroll
            for (int reg = 0; reg < 4; reg++) {
                float v = acc[mi][ni][reg];
                if (EM == E_BIAS || EM == E_BIASRELU) v += bias[ccol];
                if (EM == E_RELU || EM == E_BIASRELU) v = relu_(v);
                C[(size_t)(rbase + reg) * N + ccol] = v;
            }
        }
    }
}

// ---------- pre-split W1 left panels to bf16 hi/lo: [3][256][256] ----------
__global__ void w1split_kernel(const float* __restrict__ Wa1, const float* __restrict__ Wd1,
                               short* __restrict__ w1h, short* __restrict__ w1l)
{
    int idx = blockIdx.x * 256 + threadIdx.x;   // 3*256*256
    int which = idx >> 16, rem = idx & 65535;
    int r = rem >> 8, k = rem & 255;
    const float* W = (which == 0) ? Wa1 : (Wd1 + (size_t)(which - 1) * 256 * 512);
    float v = W[(size_t)r * 512 + k];
    short hi = f2bf(v);
    w1h[idx] = hi;
    w1l[idx] = f2bf(v - bf2f(hi));
}

// ---------- MFMA attention v2: 128 edges/block, B from pre-split global bf16 ----------
// me[e] = relu(S[src]+R[rel]+D[dst]); MODE: me = relu(me + T0[src])
// s[e] = sigmoid( tanh(me@W1L^T + term[g]) . W2 )
template<int MODE>
__global__ __launch_bounds__(256, 2)
void mattn(const float* __restrict__ S, const float* __restrict__ Rt,
           const float* __restrict__ D, const float* __restrict__ T0,
           const int* __restrict__ esrc, const int* __restrict__ erel,
           const int* __restrict__ edst,
           const short* __restrict__ w1h, const short* __restrict__ w1l,
           const float* __restrict__ W2,
           const float* __restrict__ term, float* __restrict__ sbuf)
{
    __shared__ short Ah[128][40], Al[128][40];
    __shared__ float partl[4][128];
    __shared__ int isrc[128], irel[128], idst[128];
    const int t = threadIdx.x;
    const int kc = t & 7, lr = t >> 3;
    const int lane = t & 63, wv = t >> 6;     // wave wv owns cols [wv*64, wv*64+64)
    const int frow = lane & 15, kb = (lane >> 4) * 8;
    const int r0 = blockIdx.x * 128;

    if (t < 128) {
        int e = r0 + t;
        isrc[t] = esrc[e]; irel[t] = erel[e]; idst[t] = edst[e];
    }
    __syncthreads();

    f4 acc[8][4] = {};

    for (int k0 = 0; k0 < 8; k0++) {          // 8 k-slices of 32
        const int gk = k0 * 32 + kc * 4;
        const int kk = kc * 4;
        #pragma unroll
        for (int ri = 0; ri < 4; ri++) {
            int row = lr + 32 * ri;
            int s = isrc[row], rl = irel[row], dd = idst[row];
            float4 v = relu4(add4(add4(ld4(S + (size_t)s * HD + gk),
                                       ld4(Rt + (size_t)rl * HD + gk)),
                                  ld4(D + (size_t)dd * HD + gk)));
            if (MODE) v = relu4(add4(v, ld4(T0 + (size_t)s * HD + gk)));
            bf4 h, l; split4(v, h, l);
            *(bf4*)&Ah[row][kk] = h;
            *(bf4*)&Al[row][kk] = l;
        }
        __syncthreads();
        bf8 ah[8], al[8];
        #pragma unroll
        for (int mi = 0; mi < 8; mi++) {
            ah[mi] = *(const bf8*)&Ah[mi*16 + frow][kb];
            al[mi] = *(const bf8*)&Al[mi*16 + frow][kb];
        }
        #pragma unroll
        for (int ni = 0; ni < 4; ni++) {
            int wr = wv*64 + ni*16 + frow;
            const short* wp = (const short*)w1h + (size_t)wr * 256 + k0*32 + kb;
            const short* lp = (const short*)w1l + (size_t)wr * 256 + k0*32 + kb;
            bf8 bh = *(const bf8*)wp;
            bf8 bl = *(const bf8*)lp;
            #pragma unroll
            for (int mi = 0; mi < 8; mi++) {
                acc[mi][ni] = mfma_(ah[mi], bh, acc[mi][ni]);
                acc[mi][ni] = mfma_(ah[mi], bl, acc[mi][ni]);
                acc[mi][ni] = mfma_(al[mi], bh, acc[mi][ni]);
            }
        }
        __syncthreads();
    }
    #pragma unroll
    for (int mi = 0; mi < 8; mi++) {
        #pragma unroll
        for (int reg = 0; reg < 4; reg++) {
            int rl = mi*16 + (lane >> 4) * 4 + reg;
            int g = (r0 + rl) / Eg;
            float p = 0.f;
            #pragma unroll
            for (int ni = 0; ni < 4; ni++) {
                int n = wv*64 + ni*16 + frow;
                p += tanhf(acc[mi][ni][reg] + term[g*HD + n]) * W2[n];
            }
            p += __shfl_xor(p, 1); p += __shfl_xor(p, 2);
            p += __shfl_xor(p, 4); p += __shfl_xor(p, 8);
            if (frow == 0) partl[wv][rl] = p;
        }
    }
    __syncthreads();
    if (t < 128) {
        float p = partl[0][t] + partl[1][t] + partl[2][t] + partl[3][t];
        sbuf[r0 + t] = sigm_(p);
    }
}

// ------- CSR-gather aggregation: agg[n] = sum_{e: dst[e]==n} me(e) * s[e] -------
template<int MODE>
__global__ __launch_bounds__(256)
void agg_gather(const float* __restrict__ S, const float* __restrict__ Rt,
                const float* __restrict__ D, const float* __restrict__ T0,
                const int* __restrict__ esrc, const int* __restrict__ erel,
                const int* __restrict__ rowptr, const int* __restrict__ eidx,
                const float* __restrict__ s, float* __restrict__ agg)
{
    int node = blockIdx.x * 4 + (threadIdx.x >> 6);
    int c = (threadIdx.x & 63) * 4;
    float4 dn = ld4(D + (size_t)node * HD + c);   // dst row constant per node
    float4 acc{0.f, 0.f, 0.f, 0.f};
    int beg = rowptr[node], end = rowptr[node + 1];
    for (int i = beg; i < end; i++) {
        int e = eidx[i];
        int sr = esrc[e], rl = erel[e];
        float4 v = relu4(add4(add4(ld4(S + (size_t)sr * HD + c),
                                   ld4(Rt + (size_t)rl * HD + c)), dn));
        if (MODE) v = relu4(add4(v, ld4(T0 + (size_t)sr * HD + c)));
        float sc = s[e];
        acc.x += v.x * sc; acc.y += v.y * sc;
        acc.z += v.z * sc; acc.w += v.w * sc;
    }
    st4(agg + (size_t)node * HD + c, acc);
}

// ------------- CSR build -------------
__global__ void zeroi_kernel(int* __restrict__ p)
{
    p[blockIdx.x * 256 + threadIdx.x] = 0;
}
__global__ void csr_count(const int* __restrict__ dst, int* __restrict__ cnt)
{
    int e = blockIdx.x * 256 + threadIdx.x;
    atomicAdd(&cnt[dst[e]], 1);
}
__global__ void csr_scan(const int* __restrict__ cnt, int* __restrict__ rowptr)
{
    __shared__ int ws[4];
    __shared__ int carry;
    int tid = threadIdx.x;
    if (tid == 0) carry = 0;
    __syncthreads();
    for (int i = 0; i < TNODE; i += 256) {
        int v = cnt[i + tid];
        int x = v;
        #pragma unroll
        for (int off = 1; off < 64; off <<= 1) {
            int y = __shfl_up(x, off);
            if ((tid & 63) >= off) x += y;
        }
        if ((tid & 63) == 63) ws[tid >> 6] = x;
        __syncthreads();
        int add = carry;
        int w = tid >> 6;
        for (int j = 0; j < w; j++) add += ws[j];
        rowptr[i + tid] = add + x - v;      // exclusive
        __syncthreads();
        if (tid == 255) carry = add + x;
        __syncthreads();
    }
    if (tid == 0) rowptr[TNODE] = carry;
}
__global__ void csr_fill(const int* __restrict__ dst, const int* __restrict__ rowptr,
                         int* __restrict__ fillc, int* __restrict__ eidx)
{
    int e = blockIdx.x * 256 + threadIdx.x;
    int d = dst[e];
    int slot = rowptr[d] + atomicAdd(&fillc[d], 1);
    eidx[slot] = e;
}

// ------------- per-graph attention bias terms -------------
__global__ __launch_bounds__(256)
void term_kernel(const float* __restrict__ mn, const float* __restrict__ tgt_rel,
                 const float* __restrict__ Wa1, const float* __restrict__ Wd1,
                 const int* __restrict__ srcn, const int* __restrict__ tgtn,
                 float* __restrict__ term)
{
    __shared__ float Gs[HD];
    int b = blockIdx.x % Bg;
    int which = blockIdx.x / Bg;
    int c = threadIdx.x;
    float g;
    if (which == 0)
        g = mn[(size_t)srcn[b]*HD + c] + tgt_rel[b*HD + c] - mn[(size_t)tgtn[b]*HD + c];
    else
        g = tgt_rel[b*HD + c];
    Gs[c] = g;
    __syncthreads();
    const float* W = (which == 0) ? Wa1 : (Wd1 + (size_t)(which-1)*HD*512);
    float p = 0.f;
    for (int k = 0; k < HD; k += 4) {
        float4 w = ld4(W + (size_t)c*512 + 256 + k);
        p = fmaf(Gs[k], w.x, p); p = fmaf(Gs[k+1], w.y, p);
        p = fmaf(Gs[k+2], w.z, p); p = fmaf(Gs[k+3], w.w, p);
    }
    term[(size_t)which*Bg*HD + b*HD + c] = p;
}

__global__ void tgtrel_kernel(const float* __restrict__ rel_emb, const int* __restrict__ batch_rel,
                              float* __restrict__ tgt_rel)
{
    int b = blockIdx.x, c = threadIdx.x;
    tgt_rel[b*HD + c] = rel_emb[(size_t)batch_rel[b]*REMB + c];
}

__global__ void h0_kernel(const float* __restrict__ agg2, float* __restrict__ h0)
{
    int b = blockIdx.x, c = threadIdx.x;
    float m = -1e30f;
    for (int n = 0; n < Nn; n++)
        m = fmaxf(m, agg2[((size_t)b*Nn + n)*HD + c]);
    h0[b*HD + c] = m;
}

// ------------- convert w_hh to bf16: whbf[d][row][k] -------------
__global__ void whbf_kernel(const float* __restrict__ whf, const float* __restrict__ whb,
                            short* __restrict__ whbf)
{
    int idx = blockIdx.x * 256 + threadIdx.x;   // 2*768*256
    int d = idx / (768*256), rem = idx % (768*256);
    whbf[idx] = f2bf((d ? whb : whf)[rem]);
}

// ------------- combined gi bias: bc[d] = b_ih + (r,z part of b_hh) -------------
__global__ void biascomb_kernel(const float* __restrict__ bihf, const float* __restrict__ bhhf,
                                const float* __restrict__ bihb, const float* __restrict__ bhhb,
                                float* __restrict__ bc)
{
    int i = blockIdx.x * 256 + threadIdx.x;   // 1536
    int d = i / 768, r = i % 768;
    const float* bi = d ? bihb : bihf;
    const float* bhh = d ? bhhb : bhhf;
    bc[i] = bi[r] + (r < 512 ? bhh[r] : 0.f);
}

// ------------- GRU: 16 blocks x 512 thr (8 waves); bf16 weights streamed from L2 -------------
// (round-11 config: residency attempts refused by allocator; streaming + gi prefetch is best)
__global__ __launch_bounds__(512, 2)
void gru_seq(const float* __restrict__ gi_f, const float* __restrict__ gi_b,
             const short* __restrict__ whbf,
             const float* __restrict__ bhf, const float* __restrict__ bhb,
             const float* __restrict__ h0,
             float* __restrict__ outf, float* __restrict__ outb)
{
    __shared__ float hsf[16][260];      // h state f32
    __shared__ short hsh[16][264];      // h bf16 hi
    __shared__ short hsl[16][264];      // h bf16 lo
    __shared__ float gates[768][17];    // [gate*256+h][seq]
    const int blk = blockIdx.x;         // dir*8 + grp
    const int d = blk >> 3, grp = blk & 7;
    const int tid = threadIdx.x;
    const int lane = tid & 63, wv = tid >> 6;   // 8 waves
    const int f16 = lane & 15;
    const int kb  = (lane >> 4) * 8;

    const short* wp0 = whbf + (size_t)d * 768 * 256;
    const float* gi  = d ? gi_b : gi_f;
    const float* bh  = d ? bhb : bhf;
    float* outp      = d ? outb : outf;

    const int eseq = tid >> 5, ehb = tid & 31;      // epilogue: 8 h per thread
    float bhn[8];
    #pragma unroll
    for (int hh = 0; hh < 8; hh++) bhn[hh] = bh[512 + ehb + hh * 32];

    {   // init h
        #pragma unroll
        for (int hh = 0; hh < 8; hh++) {
            int h = ehb + hh * 32;
            float v = h0[(size_t)(grp*16 + eseq) * HD + h];
            hsf[eseq][h] = v;
            short hi = f2bf(v);
            hsh[eseq][h] = hi;
            hsl[eseq][h] = f2bf(v - bf2f(hi));
        }
    }
    __syncthreads();

    for (int t = 0; t < Nn; t++) {
        int trow = d ? (Nn - 1 - t) : t;
        // --- gi prefetch (hides HBM latency under MFMA phase) ---
        float gr[8], gz[8], gn[8];
        {
            size_t girow = ((size_t)(grp*16 + eseq) * Nn + trow) * 768;
            #pragma unroll
            for (int hh = 0; hh < 8; hh++) {
                int h = ehb + hh * 32;
                gr[hh] = gi[girow + h];
                gz[hh] = gi[girow + 256 + h];
                gn[hh] = gi[girow + 512 + h];
            }
        }
        // --- MFMA: 6 n-tiles per wave, weights streamed from L2 ---
        #pragma unroll
        for (int j = 0; j < 6; j++) {
            int wr = (wv*6 + j) * 16 + f16;
            const short* wp = wp0 + (size_t)wr * 256 + kb;
            f4 acc = {};
            #pragma unroll
            for (int ks = 0; ks < 8; ks++) {
                bf8 ahi = *(const bf8*)&hsh[f16][ks*32 + kb];
                bf8 alo = *(const bf8*)&hsl[f16][ks*32 + kb];
                bf8 b = *(const bf8*)(wp + ks*32);
                acc = mfma_(ahi, b, acc);
                acc = mfma_(alo, b, acc);
            }
            #pragma unroll
            for (int reg = 0; reg < 4; reg++)
                gates[(wv*6 + j)*16 + f16][(lane >> 4)*4 + reg] = acc[reg];
        }
        __syncthreads();
        // --- epilogue: thread owns (eseq, ehb + hh*32); gi already includes b_hh r/z ---
        {
            size_t orow = ((size_t)(grp*16 + eseq) * Nn + trow) * HD;
            #pragma unroll
            for (int hh = 0; hh < 8; hh++) {
                int h = ehb + hh * 32;
                float R  = gates[h][eseq];
                float Z  = gates[256 + h][eseq];
                float NN = gates[512 + h][eseq];
                float hprev = hsf[eseq][h];
                float r = sigm_(gr[hh] + R);
                float z = sigm_(gz[hh] + Z);
                float n = tanhf(gn[hh] + r * (NN + bhn[hh]));
                float nh = (1.f - z) * n + z * hprev;
                hsf[eseq][h] = nh;
                short hi = f2bf(nh);
                hsh[eseq][h] = hi;
                hsl[eseq][h] = f2bf(nh - bf2f(hi));
                outp[orow + h] = nh;
            }
        }
        __syncthreads();
    }
}

__global__ __launch_bounds__(256)
void final_kernel(const float* __restrict__ atom_h, const float* __restrict__ tgt_rel,
                  const int* __restrict__ srcn, const int* __restrict__ tgtn,
                  const float* __restrict__ Wl, const float* __restrict__ bl,
                  float* __restrict__ out)
{
    __shared__ float red[4];
    int b = blockIdx.x, c = threadIdx.x;
    float v = tanhf(atom_h[(size_t)srcn[b]*HD + c] + tgt_rel[b*HD + c]
                    - atom_h[(size_t)tgtn[b]*HD + c]);
    float p = v * Wl[c];
    #pragma unroll
    for (int off = 1; off < 64; off <<= 1) p += __shfl_xor(p, off);
    int wv = c >> 6;
    if ((c & 63) == 0) red[wv] = p;
    __syncthreads();
    if (c == 0) out[b] = red[0] + red[1] + red[2] + red[3] + bl[0];
}

extern "C" void kernel_launch(void* const* d_in, const int* in_sizes, int n_in,
                              void* d_out, int out_size, void* d_ws, size_t ws_size,
                              hipStream_t stream)
{
    const float* node_feat = (const float*)d_in[0];
    const float* rel_emb   = (const float*)d_in[1];
    const float* W_i_node  = (const float*)d_in[2];
    const float* W_i_edge  = (const float*)d_in[3];
    const float* Wa1       = (const float*)d_in[4];
    const float* Wa2       = (const float*)d_in[5];
    const float* W_h_atom  = (const float*)d_in[6];
    const float* W_h_bond  = (const float*)d_in[7];
    const float* Wd1       = (const float*)d_in[8];
    const float* Wd2       = (const float*)d_in[9];
    const float* W_comm    = (const float*)d_in[10];
    const float* gru_bias  = (const float*)d_in[11];
    const float* w_ih_f    = (const float*)d_in[12];
    const float* w_hh_f    = (const float*)d_in[13];
    const float* b_ih_f    = (const float*)d_in[14];
    const float* b_hh_f    = (const float*)d_in[15];
    const float* w_ih_b    = (const float*)d_in[16];
    const float* w_hh_b    = (const float*)d_in[17];
    const float* b_ih_b    = (const float*)d_in[18];
    const float* b_hh_b    = (const float*)d_in[19];
    const float* W_o       = (const float*)d_in[20];
    const float* b_o       = (const float*)d_in[21];
    const float* W_lin1    = (const float*)d_in[22];
    const float* b_lin1    = (const float*)d_in[23];
    const int* edge_src  = (const int*)d_in[24];
    const int* edge_dst  = (const int*)d_in[25];
    const int* edge_rel  = (const int*)d_in[26];
    const int* batch_rel = (const int*)d_in[27];
    const int* src_node  = (const int*)d_in[28];
    const int* tgt_node  = (const int*)d_in[29];
    float* out = (float*)d_out;

    float* ws = (float*)d_ws;
    size_t off = 0;
    auto alloc = [&](size_t n){ float* p = ws + off; off += n; return p; };
    float* tgt_rel    = alloc((size_t)Bg*HD);
    float* term       = alloc((size_t)3*Bg*HD);
    float* input_node = alloc((size_t)TNODE*HD);
    float* mn_a       = alloc((size_t)TNODE*HD);
    float* mn_b       = alloc((size_t)TNODE*HD);
    float* agg        = alloc((size_t)TNODE*HD);
    float* h0v        = alloc((size_t)Bg*HD);
    short* whbf       = (short*)alloc((size_t)2*768*256/2);
    short* w1h        = (short*)alloc((size_t)3*256*256/2);
    short* w1l        = (short*)alloc((size_t)3*256*256/2);
    float* bcomb      = alloc((size_t)2*768);
    float* sbuf       = alloc((size_t)TEDGE);
    int*   cnt        = (int*)alloc((size_t)TNODE);
    int*   fillc      = (int*)alloc((size_t)TNODE);
    int*   rowptr     = (int*)alloc((size_t)TNODE + 256);
    int*   eidx       = (int*)alloc((size_t)TEDGE);
    float* Sbuf       = alloc((size_t)TNODE*HD);
    float* Dbuf       = alloc((size_t)TNODE*HD);
    float* Rbuf       = alloc((size_t)256*HD);
    float* gi_f       = alloc((size_t)TNODE*768);
    float* gi_b       = alloc((size_t)TNODE*768);
    float* out_f      = alloc((size_t)TNODE*HD);
    float* out_b      = alloc((size_t)TNODE*HD);
    // aliases (lifetimes disjoint):
    float* agg2   = mn_a;        // after last attn/gather
    float* atom_h = input_node;  // after W_comm GEMM

    tgtrel_kernel<<<Bg, 256, 0, stream>>>(rel_emb, batch_rel, tgt_rel);
    whbf_kernel<<<1536, 256, 0, stream>>>(w_hh_f, w_hh_b, whbf);
    w1split_kernel<<<768, 256, 0, stream>>>(Wa1, Wd1, w1h, w1l);
    biascomb_kernel<<<6, 256, 0, stream>>>(b_ih_f, b_hh_f, b_ih_b, b_hh_b, bcomb);

    // ---- CSR build (dst-sorted incidence) ----
    zeroi_kernel<<<2*TNODE/256, 256, 0, stream>>>(cnt);     // zeros cnt AND fillc (adjacent)
    csr_count<<<TEDGE/256, 256, 0, stream>>>(edge_dst, cnt);
    csr_scan<<<1, 256, 0, stream>>>(cnt, rowptr);
    csr_fill<<<TEDGE/256, 256, 0, stream>>>(edge_dst, rowptr, fillc, eidx);

    // input_node = relu(node_feat @ W_i_node^T)
    mgemm<A_PLAIN, E_RELU><<<dim3(HD/128, TNODE/128), 256, 0, stream>>>(
        node_feat, nullptr, nullptr, W_i_node, nullptr, input_node,
        TNODE, HD, NEMB, NEMB, NEMB);

    // edge-feature factor tables: ie[e] = relu(S[src] + R[rel] + D[dst])
    mgemm<A_PLAIN, E_STORE><<<dim3(HD/128, TNODE/128), 256, 0, stream>>>(
        node_feat, nullptr, nullptr, W_i_edge + 0, nullptr, Sbuf,
        TNODE, HD, NEMB, NEMB, 512);
    mgemm<A_PLAIN, E_STORE><<<dim3(HD/128, TNODE/128), 256, 0, stream>>>(
        node_feat, nullptr, nullptr, W_i_edge + 384, nullptr, Dbuf,
        TNODE, HD, NEMB, NEMB, 512);
    mgemm<A_CLAMP, E_STORE><<<dim3(HD/128, 2), 256, 0, stream>>>(
        rel_emb, nullptr, nullptr, W_i_edge + 128, nullptr, Rbuf,
        200, HD, REMB, REMB, 512);

    term_kernel<<<3*Bg, 256, 0, stream>>>(input_node, tgt_rel, Wa1, Wd1,
                                          src_node, tgt_node, term);

    // ---- input attention scale + gather-aggregate ----
    mattn<0><<<TEDGE/128, 256, 0, stream>>>(Sbuf, Rbuf, Dbuf, Sbuf,
        edge_src, edge_rel, edge_dst, w1h, w1l, Wa2, term, sbuf);
    agg_gather<0><<<TNODE/4, 256, 0, stream>>>(Sbuf, Rbuf, Dbuf, Sbuf,
        edge_src, edge_rel, rowptr, eidx, sbuf, agg);

    const float* mn_cur = input_node;
    float* bufs[2] = {mn_a, mn_b};
    for (int d = 0; d < 2; d++) {
        float* mn_next = bufs[d];
        float* tmp     = bufs[1-d];
        mgemm<A_ADD, E_RELU><<<dim3(2, TNODE/128), 256, 0, stream>>>(
            mn_cur, agg, nullptr, W_h_atom + (size_t)d*HD*HD, nullptr, mn_next,
            TNODE, HD, HD, HD, HD);
        mgemm<A_PLAIN, E_STORE><<<dim3(2, TNODE/128), 256, 0, stream>>>(
            mn_next, nullptr, nullptr, W_h_bond + (size_t)d*HD*HD, nullptr, tmp,
            TNODE, HD, HD, HD, HD);
        mattn<1><<<TEDGE/128, 256, 0, stream>>>(Sbuf, Rbuf, Dbuf, tmp,
            edge_src, edge_rel, edge_dst, w1h + (size_t)(1+d)*65536,
            w1l + (size_t)(1+d)*65536, Wd2 + (size_t)d*HD,
            term + (size_t)(1+d)*Bg*HD, sbuf);
        agg_gather<1><<<TNODE/4, 256, 0, stream>>>(Sbuf, Rbuf, Dbuf, tmp,
            edge_src, edge_rel, rowptr, eidx, sbuf, agg);
        mn_cur = mn_next;
    }

    // agg2 = concat([agg, mn, input_node]) @ W_comm^T   (agg2 aliases mn_a)
    mgemm<A_CAT3, E_STORE><<<dim3(2, TNODE/128), 256, 0, stream>>>(
        agg, (const float*)mn_cur, input_node, W_comm, nullptr, agg2,
        TNODE, HD, 3*HD, 0, 3*HD);

    h0_kernel<<<Bg, 256, 0, stream>>>(agg2, h0v);

    // gi = relu(agg2 + gru_bias) @ w_ih^T + (b_ih + b_hh[r,z])   (both directions)
    mgemm<A_RELUB, E_BIAS><<<dim3(768/128, TNODE/128), 256, 0, stream>>>(
        agg2, gru_bias, nullptr, w_ih_f, bcomb, gi_f,
        TNODE, 768, HD, HD, HD);
    mgemm<A_RELUB, E_BIAS><<<dim3(768/128, TNODE/128), 256, 0, stream>>>(
        agg2, gru_bias, nullptr, w_ih_b, bcomb + 768, gi_b,
        TNODE, 768, HD, HD, HD);

    gru_seq<<<16, 512, 0, stream>>>(gi_f, gi_b, whbf, b_hh_f, b_hh_b, h0v,
                                    out_f, out_b);

    // atom_h = relu(relu(concat(out_f,out_b)) @ W_o^T + b_o)
    mgemm<A_CAT2R, E_BIASRELU><<<dim3(2, TNODE/128), 256, 0, stream>>>(
        out_f, out_b, nullptr, W_o, b_o, atom_h,
        TNODE, HD, 2*HD, 0, 2*HD);

    final_kernel<<<Bg, 256, 0, stream>>>(atom_h, tgt_rel, src_node, tgt_node,
                                         W_lin1, b_lin1, out);
}